// Round 1
// baseline (249.289 us; speedup 1.0000x reference)
//
#include <hip/hip_runtime.h>

typedef unsigned short u16;
typedef __attribute__((ext_vector_type(8))) short bf16x8;
typedef __attribute__((ext_vector_type(4))) float f32x4;

struct __align__(8) us4 { u16 x, y, z, w; };

#define B_  4
#define S_  1024
#define D_  1024
#define H_  16
#define DK_ 64

__device__ __forceinline__ u16 f2bf(float x) {
    union { float f; unsigned int u; } c; c.f = x;
    unsigned int r = (c.u + 0x7FFFu + ((c.u >> 16) & 1u)) >> 16;
    return (u16)r;
}

__device__ __forceinline__ void gload_lds16(const void* g, void* l) {
    __builtin_amdgcn_global_load_lds(
        (const __attribute__((address_space(1))) unsigned int*)g,
        (__attribute__((address_space(3))) unsigned int*)l, 16, 0, 0);
}

// ---------------- convert f32 -> bf16 (x tensors) ----------------
__global__ __launch_bounds__(256) void cvt_x(const float* __restrict__ q,
                                             const float* __restrict__ k,
                                             const float* __restrict__ v,
                                             u16* __restrict__ xq,
                                             u16* __restrict__ xk,
                                             u16* __restrict__ xv) {
    const float* src = (blockIdx.y == 0) ? q : (blockIdx.y == 1) ? k : v;
    u16* dst        = (blockIdx.y == 0) ? xq : (blockIdx.y == 1) ? xk : xv;
    int idx = (blockIdx.x * 256 + threadIdx.x) * 4;
    f32x4 f = *(const f32x4*)(src + idx);
    us4 o; o.x = f2bf(f[0]); o.y = f2bf(f[1]); o.z = f2bf(f[2]); o.w = f2bf(f[3]);
    *(us4*)(dst + idx) = o;
}

// ---------------- convert+transpose weights: WT[n][k] = W[k][n], bf16 ----------------
__global__ __launch_bounds__(256) void cvt_w(const float* __restrict__ w0, const float* __restrict__ w1,
                                             const float* __restrict__ w2, const float* __restrict__ w3,
                                             u16* __restrict__ t0, u16* __restrict__ t1,
                                             u16* __restrict__ t2, u16* __restrict__ t3) {
    __shared__ float t[64][65];
    const float* W = (blockIdx.z == 0) ? w0 : (blockIdx.z == 1) ? w1 : (blockIdx.z == 2) ? w2 : w3;
    u16* T        = (blockIdx.z == 0) ? t0 : (blockIdx.z == 1) ? t1 : (blockIdx.z == 2) ? t2 : t3;
    int k0 = blockIdx.x * 64, n0 = blockIdx.y * 64;
    int tid = threadIdx.x;
    int r4 = tid >> 6, c = tid & 63;
#pragma unroll
    for (int i = 0; i < 16; i++) {
        int r = i * 4 + r4;
        t[r][c] = W[(size_t)(k0 + r) * 1024 + n0 + c];
    }
    __syncthreads();
#pragma unroll
    for (int i = 0; i < 16; i++) {
        int r = i * 4 + r4;
        T[(size_t)(n0 + r) * 1024 + k0 + c] = f2bf(t[c][r]);
    }
}

// ---------------- 128x128 bf16 MFMA GEMM, X[4096][1024] @ WT[1024][1024]^T ----------------
// mode 0: out bf16 head layout [B,H,S,DK]   (scale applied after bias; used for Q (0.125) / K (1))
// mode 1: out bf16 transposed  [B,H,DK,S]   (V)
// mode 2: out f32 [4096][1024]               (final projection)
__device__ __forceinline__ void gemm_core(const u16* __restrict__ X, const u16* __restrict__ WT,
                                          const float* __restrict__ bias, void* __restrict__ outp,
                                          int mode, float scale, int bm, int bn) {
    __shared__ u16 Al[128 * 32];
    __shared__ u16 Bl[128 * 32];
    int tid = threadIdx.x, l = tid & 63, w = tid >> 6;
    int lr = l & 15, lq = l >> 4;
    int wm = (w >> 1) * 64, wn = (w & 1) * 64;
    f32x4 acc[4][4] = {};
    for (int kk = 0; kk < 1024; kk += 32) {
        __syncthreads();
#pragma unroll
        for (int i = 0; i < 2; i++) {
            int flat = tid * 16 + i * 4096;
            int row = flat >> 6, kb = flat & 63;
            gload_lds16((const char*)X + ((size_t)(bm * 128 + row) * 2048 + (size_t)kk * 2 + kb),
                        (char*)Al + flat);
            gload_lds16((const char*)WT + ((size_t)(bn * 128 + row) * 2048 + (size_t)kk * 2 + kb),
                        (char*)Bl + flat);
        }
        asm volatile("s_waitcnt vmcnt(0)" ::: "memory");
        __syncthreads();
        bf16x8 af[4], bfr[4];
#pragma unroll
        for (int ms = 0; ms < 4; ms++)
            af[ms] = *(const bf16x8*)(Al + (wm + ms * 16 + lr) * 32 + lq * 8);
#pragma unroll
        for (int ns = 0; ns < 4; ns++)
            bfr[ns] = *(const bf16x8*)(Bl + (wn + ns * 16 + lr) * 32 + lq * 8);
#pragma unroll
        for (int ms = 0; ms < 4; ms++)
#pragma unroll
            for (int ns = 0; ns < 4; ns++)
                acc[ms][ns] = __builtin_amdgcn_mfma_f32_16x16x32_bf16(af[ms], bfr[ns], acc[ms][ns], 0, 0, 0);
    }
#pragma unroll
    for (int ns = 0; ns < 4; ns++) {
        int n = bn * 128 + wn + ns * 16 + lr;
        float bv_ = bias[n];
#pragma unroll
        for (int ms = 0; ms < 4; ms++) {
            int mbase = bm * 128 + wm + ms * 16 + lq * 4;
            if (mode == 0) {
                u16* o = (u16*)outp;
                int h = n >> 6, dk = n & 63;
#pragma unroll
                for (int r = 0; r < 4; r++) {
                    int m = mbase + r;
                    int b = m >> 10, s = m & 1023;
                    o[((size_t)(b * H_ + h) * 1024 + s) * 64 + dk] = f2bf((acc[ms][ns][r] + bv_) * scale);
                }
            } else if (mode == 1) {
                u16* o = (u16*)outp;
                int h = n >> 6, dk = n & 63;
                int b = mbase >> 10, s0 = mbase & 1023;
                us4 pk;
                pk.x = f2bf(acc[ms][ns][0] + bv_);
                pk.y = f2bf(acc[ms][ns][1] + bv_);
                pk.z = f2bf(acc[ms][ns][2] + bv_);
                pk.w = f2bf(acc[ms][ns][3] + bv_);
                *(us4*)(o + ((size_t)(b * H_ + h) * 64 + dk) * 1024 + s0) = pk;
            } else {
                float* o = (float*)outp;
#pragma unroll
                for (int r = 0; r < 4; r++) {
                    int m = mbase + r;
                    o[(size_t)m * 1024 + n] = acc[ms][ns][r] + bv_;
                }
            }
        }
    }
}

__global__ __launch_bounds__(256) void gemm_qkv(const u16* __restrict__ Xq, const u16* __restrict__ Xk,
                                                const u16* __restrict__ Xv,
                                                const u16* __restrict__ Wq, const u16* __restrict__ Wk,
                                                const u16* __restrict__ Wv,
                                                const float* __restrict__ bq, const float* __restrict__ bk,
                                                const float* __restrict__ bv,
                                                u16* __restrict__ Qh, u16* __restrict__ Kh,
                                                u16* __restrict__ VT) {
    int z = blockIdx.z;
    const u16* X = (z == 0) ? Xq : (z == 1) ? Xk : Xv;
    const u16* W = (z == 0) ? Wq : (z == 1) ? Wk : Wv;
    const float* bia = (z == 0) ? bq : (z == 1) ? bk : bv;
    void* out = (z == 0) ? (void*)Qh : (z == 1) ? (void*)Kh : (void*)VT;
    int mode = (z == 2) ? 1 : 0;
    float scale = (z == 0) ? 0.125f : 1.0f;
    gemm_core(X, W, bia, out, mode, scale, blockIdx.x, blockIdx.y);
}

__global__ __launch_bounds__(256) void gemm_out(const u16* __restrict__ X, const u16* __restrict__ WT,
                                                const float* __restrict__ bias, float* __restrict__ outp) {
    gemm_core(X, WT, bias, outp, 2, 1.0f, blockIdx.x, blockIdx.y);
}

// ---------------- fused attention: scores -> softmax -> attn write -> PV ----------------
// block: 16 q-rows of one (b,h); 4 waves, each covering 256 keys.
__global__ __launch_bounds__(256) void attn_fused(const u16* __restrict__ Qh, const u16* __restrict__ Kh,
                                                  const u16* __restrict__ VT,
                                                  float* __restrict__ attn_out, float* __restrict__ x_out) {
    __shared__ u16 P_lds[4][4096];      // [wave][16 rows x 256 keys], col XOR-swizzled
    __shared__ float red[4][16][64];    // PV cross-wave reduce
    __shared__ float redm[4][16];
    __shared__ float reds[4][16];
    int tid = threadIdx.x, l = tid & 63, w = tid >> 6;
    int lr = l & 15, lq = l >> 4;
    int q0 = blockIdx.x * 16, bh = blockIdx.y;
    const u16* qp = Qh + (size_t)bh * 65536;
    const u16* kp = Kh + (size_t)bh * 65536;
    const u16* vp = VT + (size_t)bh * 65536;

    bf16x8 aq0 = *(const bf16x8*)(qp + (q0 + lr) * 64 + lq * 8);
    bf16x8 aq1 = *(const bf16x8*)(qp + (q0 + lr) * 64 + 32 + lq * 8);

    f32x4 sc[16];
#pragma unroll
    for (int n = 0; n < 16; n++) {
        int kb = w * 256 + n * 16;
        bf16x8 b0 = *(const bf16x8*)(kp + (size_t)(kb + lr) * 64 + lq * 8);
        bf16x8 b1 = *(const bf16x8*)(kp + (size_t)(kb + lr) * 64 + 32 + lq * 8);
        f32x4 a = {};
        a = __builtin_amdgcn_mfma_f32_16x16x32_bf16(aq0, b0, a, 0, 0, 0);
        a = __builtin_amdgcn_mfma_f32_16x16x32_bf16(aq1, b1, a, 0, 0, 0);
        sc[n] = a;
    }

    // row max: per-lane over 16 subtiles, then across the 16 lanes of the quarter, then across waves
#pragma unroll
    for (int r = 0; r < 4; r++) {
        float m = sc[0][r];
#pragma unroll
        for (int n = 1; n < 16; n++) m = fmaxf(m, sc[n][r]);
#pragma unroll
        for (int off = 1; off < 16; off <<= 1) m = fmaxf(m, __shfl_xor(m, off));
        if (lr == 0) redm[w][lq * 4 + r] = m;
    }
    __syncthreads();
    float inv[4];
#pragma unroll
    for (int r = 0; r < 4; r++) {
        int row = lq * 4 + r;
        float M = fmaxf(fmaxf(redm[0][row], redm[1][row]), fmaxf(redm[2][row], redm[3][row]));
        float s = 0.f;
#pragma unroll
        for (int n = 0; n < 16; n++) {
            float p = __expf(sc[n][r] - M);
            sc[n][r] = p;
            s += p;
        }
#pragma unroll
        for (int off = 1; off < 16; off <<= 1) s += __shfl_xor(s, off);
        if (lr == 0) reds[w][row] = s;
    }
    __syncthreads();
#pragma unroll
    for (int r = 0; r < 4; r++) {
        int row = lq * 4 + r;
        inv[r] = 1.0f / (reds[0][row] + reds[1][row] + reds[2][row] + reds[3][row]);
    }

    // write attn (f32, d_out) + stage P (bf16) into swizzled LDS for layout conversion
    size_t abase = (size_t)bh * 1048576 + (size_t)q0 * 1024 + w * 256;
#pragma unroll
    for (int n = 0; n < 16; n++) {
#pragma unroll
        for (int r = 0; r < 4; r++) {
            float p = sc[n][r] * inv[r];
            attn_out[abase + (size_t)(lq * 4 + r) * 1024 + n * 16 + lr] = p;
            int row = lq * 4 + r, col = n * 16 + lr;
            P_lds[w][row * 256 + (col ^ ((row & 3) << 4))] = f2bf(p);
        }
    }
    __syncthreads();

    // PV: P[16 x 256] @ V^T-slice -> [16 x 64] partial per wave
    f32x4 pv[4] = {};
#pragma unroll
    for (int kk = 0; kk < 8; kk++) {
        int col = kk * 32 + lq * 8;
        bf16x8 ap = *(const bf16x8*)(&P_lds[w][lr * 256 + (col ^ ((lr & 3) << 4))]);
#pragma unroll
        for (int ns = 0; ns < 4; ns++) {
            bf16x8 bv_ = *(const bf16x8*)(vp + (size_t)(ns * 16 + lr) * 1024 + w * 256 + kk * 32 + lq * 8);
            pv[ns] = __builtin_amdgcn_mfma_f32_16x16x32_bf16(ap, bv_, pv[ns], 0, 0, 0);
        }
    }
#pragma unroll
    for (int ns = 0; ns < 4; ns++)
#pragma unroll
        for (int r = 0; r < 4; r++)
            red[w][lq * 4 + r][ns * 16 + lr] = pv[ns][r];
    __syncthreads();

    int qq = tid >> 4, dk = (tid & 15) * 4;
    f32x4 acc = *(const f32x4*)&red[0][qq][dk];
#pragma unroll
    for (int w2 = 1; w2 < 4; w2++) acc += *(const f32x4*)&red[w2][qq][dk];
    int b = bh >> 4, h = bh & 15;
    *(f32x4*)(x_out + ((size_t)(b * 1024 + q0 + qq)) * 1024 + h * 64 + dk) = acc;
}

// ---------------- residual + LayerNorm -> bf16 ----------------
__global__ __launch_bounds__(256) void ln_kernel(const float* __restrict__ x, const float* __restrict__ resid,
                                                 const float* __restrict__ gamma, const float* __restrict__ beta,
                                                 u16* __restrict__ out) {
    int row = blockIdx.x, tid = threadIdx.x;
    int l = tid & 63, w = tid >> 6;
    size_t base = (size_t)row * 1024 + tid * 4;
    f32x4 v = *(const f32x4*)(x + base);
    f32x4 rz = *(const f32x4*)(resid + base);
    v += rz;
    float s = v[0] + v[1] + v[2] + v[3];
    float s2 = v[0] * v[0] + v[1] * v[1] + v[2] * v[2] + v[3] * v[3];
#pragma unroll
    for (int off = 1; off < 64; off <<= 1) {
        s += __shfl_xor(s, off);
        s2 += __shfl_xor(s2, off);
    }
    __shared__ float as_[4], as2_[4];
    if (l == 0) { as_[w] = s; as2_[w] = s2; }
    __syncthreads();
    s = as_[0] + as_[1] + as_[2] + as_[3];
    s2 = as2_[0] + as2_[1] + as2_[2] + as2_[3];
    float mean = s * (1.f / 1024.f);
    float var = s2 * (1.f / 1024.f) - mean * mean;
    float rs = rsqrtf(var + 1e-6f);
    f32x4 g = *(const f32x4*)(gamma + tid * 4);
    f32x4 bt = *(const f32x4*)(beta + tid * 4);
    us4 o;
    o.x = f2bf((v[0] - mean) * rs * g[0] + bt[0]);
    o.y = f2bf((v[1] - mean) * rs * g[1] + bt[1]);
    o.z = f2bf((v[2] - mean) * rs * g[2] + bt[2]);
    o.w = f2bf((v[3] - mean) * rs * g[3] + bt[3]);
    *(us4*)(out + base) = o;
}

extern "C" void kernel_launch(void* const* d_in, const int* in_sizes, int n_in,
                              void* d_out, int out_size, void* d_ws, size_t ws_size,
                              hipStream_t stream) {
    const float* query = (const float*)d_in[0];
    const float* key   = (const float*)d_in[1];
    const float* value = (const float*)d_in[2];
    const float* Wq    = (const float*)d_in[3];
    const float* bq    = (const float*)d_in[4];
    const float* Wk    = (const float*)d_in[5];
    const float* bk    = (const float*)d_in[6];
    const float* Wv    = (const float*)d_in[7];
    const float* bv    = (const float*)d_in[8];
    const float* Wo    = (const float*)d_in[9];
    const float* bo    = (const float*)d_in[10];
    const float* gamma = (const float*)d_in[11];
    const float* beta  = (const float*)d_in[12];

    char* ws = (char*)d_ws;
    // ws layout (bytes):
    u16* XQ  = (u16*)(ws + 0);          // 8 MiB  bf16 [4096][1024]
    u16* XK  = (u16*)(ws + 8388608);    // 8 MiB
    u16* XV  = (u16*)(ws + 16777216);   // 8 MiB
    u16* WQT = (u16*)(ws + 25165824);   // 2 MiB each
    u16* WKT = (u16*)(ws + 27262976);
    u16* WVT = (u16*)(ws + 29360128);
    u16* WOT = (u16*)(ws + 31457280);
    u16* Qh  = (u16*)(ws + 33554432);   // 8 MiB bf16 [B,H,S,DK] (pre-scaled by 1/8)
    u16* Kh  = (u16*)(ws + 41943040);   // 8 MiB bf16 [B,H,S,DK]
    u16* VT  = (u16*)(ws + 50331648);   // 8 MiB bf16 [B,H,DK,S]
    float* PV = (float*)(ws + 0);        // 16 MiB f32 [B,S,D] — overlaps XQ/XK (dead by then)
    u16* LN  = (u16*)(ws + 16777216);   // 8 MiB bf16 — overlaps XV (dead by then)

    float* outp = (float*)d_out;
    float* attn = outp + 4194304;

    cvt_x<<<dim3(4096, 3), 256, 0, stream>>>(query, key, value, XQ, XK, XV);
    cvt_w<<<dim3(16, 16, 4), 256, 0, stream>>>(Wq, Wk, Wv, Wo, WQT, WKT, WVT, WOT);
    gemm_qkv<<<dim3(32, 8, 3), 256, 0, stream>>>(XQ, XK, XV, WQT, WKT, WVT, bq, bk, bv, Qh, Kh, VT);
    attn_fused<<<dim3(64, 64), 256, 0, stream>>>(Qh, Kh, VT, attn, PV);
    ln_kernel<<<4096, 256, 0, stream>>>(PV, query, gamma, beta, LN);
    gemm_out<<<dim3(32, 8), 256, 0, stream>>>(LN, WOT, bo, outp);
}

// Round 2
// 245.821 us; speedup vs baseline: 1.0141x; 1.0141x over previous
//
#include <hip/hip_runtime.h>

typedef unsigned short u16;
typedef __attribute__((ext_vector_type(8))) short bf16x8;
typedef __attribute__((ext_vector_type(4))) float f32x4;

struct __align__(8) us4 { u16 x, y, z, w; };

#define B_  4
#define S_  1024
#define D_  1024
#define H_  16
#define DK_ 64

__device__ __forceinline__ u16 f2bf(float x) {
    union { float f; unsigned int u; } c; c.f = x;
    unsigned int r = (c.u + 0x7FFFu + ((c.u >> 16) & 1u)) >> 16;
    return (u16)r;
}

__device__ __forceinline__ void gload_lds16(const void* g, void* l) {
    __builtin_amdgcn_global_load_lds(
        (const __attribute__((address_space(1))) unsigned int*)g,
        (__attribute__((address_space(3))) unsigned int*)l, 16, 0, 0);
}

// ---------------- convert f32 -> bf16 (x tensors) ----------------
__global__ __launch_bounds__(256) void cvt_x(const float* __restrict__ q,
                                             const float* __restrict__ k,
                                             const float* __restrict__ v,
                                             u16* __restrict__ xq,
                                             u16* __restrict__ xk,
                                             u16* __restrict__ xv) {
    const float* src = (blockIdx.y == 0) ? q : (blockIdx.y == 1) ? k : v;
    u16* dst        = (blockIdx.y == 0) ? xq : (blockIdx.y == 1) ? xk : xv;
    int idx = (blockIdx.x * 256 + threadIdx.x) * 4;
    f32x4 f = *(const f32x4*)(src + idx);
    us4 o; o.x = f2bf(f[0]); o.y = f2bf(f[1]); o.z = f2bf(f[2]); o.w = f2bf(f[3]);
    *(us4*)(dst + idx) = o;
}

// ---------------- convert+transpose weights: WT[n][k] = W[k][n], bf16 ----------------
__global__ __launch_bounds__(256) void cvt_w(const float* __restrict__ w0, const float* __restrict__ w1,
                                             const float* __restrict__ w2, const float* __restrict__ w3,
                                             u16* __restrict__ t0, u16* __restrict__ t1,
                                             u16* __restrict__ t2, u16* __restrict__ t3) {
    __shared__ float t[64][65];
    const float* W = (blockIdx.z == 0) ? w0 : (blockIdx.z == 1) ? w1 : (blockIdx.z == 2) ? w2 : w3;
    u16* T        = (blockIdx.z == 0) ? t0 : (blockIdx.z == 1) ? t1 : (blockIdx.z == 2) ? t2 : t3;
    int k0 = blockIdx.x * 64, n0 = blockIdx.y * 64;
    int tid = threadIdx.x;
    int r4 = tid >> 6, c = tid & 63;
#pragma unroll
    for (int i = 0; i < 16; i++) {
        int r = i * 4 + r4;
        t[r][c] = W[(size_t)(k0 + r) * 1024 + n0 + c];
    }
    __syncthreads();
#pragma unroll
    for (int i = 0; i < 16; i++) {
        int r = i * 4 + r4;
        T[(size_t)(n0 + r) * 1024 + k0 + c] = f2bf(t[c][r]);
    }
}

// ---------------- 128xBN bf16 MFMA GEMM, BK=64, X[4096][1024] @ WT[1024][1024]^T ----------------
// MODE 0: out bf16 head layout [B,H,S,DK]   (scale applied after bias; Q (0.125) / K (1))
// MODE 1: out bf16 transposed  [B,H,DK,S]   (V)
// MODE 2: out f32 [4096][1024]               (final projection)
template <int BN, int MODE>
__device__ __forceinline__ void gemm_core(const u16* __restrict__ X, const u16* __restrict__ WT,
                                          const float* __restrict__ bias, void* __restrict__ outp,
                                          float scale, int bm, int bn) {
    constexpr int NS = BN / 32;          // acc cols per wave
    __shared__ u16 Al[128 * 64];
    __shared__ u16 Bl[BN * 64];
    int tid = threadIdx.x, l = tid & 63, w = tid >> 6;
    int lr = l & 15, lq = l >> 4;
    int wm = (w >> 1) * 64, wn = (w & 1) * (BN / 2);
    f32x4 acc[4][NS] = {};
    for (int kk = 0; kk < 1024; kk += 64) {
        __syncthreads();
#pragma unroll
        for (int i = 0; i < 4; i++) {   // A tile: 128x64 bf16 = 16KB
            int flat = tid * 16 + i * 4096;
            int row = flat >> 7, kb = flat & 127;
            gload_lds16((const char*)X + ((size_t)(bm * 128 + row) * 2048 + (size_t)kk * 2 + kb),
                        (char*)Al + flat);
        }
#pragma unroll
        for (int i = 0; i < BN / 32; i++) {  // B tile: BNx64 bf16
            int flat = tid * 16 + i * 4096;
            int row = flat >> 7, kb = flat & 127;
            gload_lds16((const char*)WT + ((size_t)(bn * BN + row) * 2048 + (size_t)kk * 2 + kb),
                        (char*)Bl + flat);
        }
        asm volatile("s_waitcnt vmcnt(0)" ::: "memory");
        __syncthreads();
#pragma unroll
        for (int kkk = 0; kkk < 2; kkk++) {
            bf16x8 af[4], bfr[NS];
#pragma unroll
            for (int ms = 0; ms < 4; ms++)
                af[ms] = *(const bf16x8*)(Al + (wm + ms * 16 + lr) * 64 + kkk * 32 + lq * 8);
#pragma unroll
            for (int ns = 0; ns < NS; ns++)
                bfr[ns] = *(const bf16x8*)(Bl + (wn + ns * 16 + lr) * 64 + kkk * 32 + lq * 8);
#pragma unroll
            for (int ms = 0; ms < 4; ms++)
#pragma unroll
                for (int ns = 0; ns < NS; ns++)
                    acc[ms][ns] = __builtin_amdgcn_mfma_f32_16x16x32_bf16(af[ms], bfr[ns], acc[ms][ns], 0, 0, 0);
        }
    }
#pragma unroll
    for (int ns = 0; ns < NS; ns++) {
        int n = bn * BN + wn + ns * 16 + lr;
        float bv_ = bias[n];
#pragma unroll
        for (int ms = 0; ms < 4; ms++) {
            int mbase = bm * 128 + wm + ms * 16 + lq * 4;
            if (MODE == 0) {
                u16* o = (u16*)outp;
                int h = n >> 6, dk = n & 63;
#pragma unroll
                for (int r = 0; r < 4; r++) {
                    int m = mbase + r;
                    int b = m >> 10, s = m & 1023;
                    o[((size_t)(b * H_ + h) * 1024 + s) * 64 + dk] = f2bf((acc[ms][ns][r] + bv_) * scale);
                }
            } else if (MODE == 1) {
                u16* o = (u16*)outp;
                int h = n >> 6, dk = n & 63;
                int b = mbase >> 10, s0 = mbase & 1023;
                us4 pk;
                pk.x = f2bf(acc[ms][ns][0] + bv_);
                pk.y = f2bf(acc[ms][ns][1] + bv_);
                pk.z = f2bf(acc[ms][ns][2] + bv_);
                pk.w = f2bf(acc[ms][ns][3] + bv_);
                *(us4*)(o + ((size_t)(b * H_ + h) * 64 + dk) * 1024 + s0) = pk;
            } else {
                float* o = (float*)outp;
#pragma unroll
                for (int r = 0; r < 4; r++) {
                    int m = mbase + r;
                    o[(size_t)m * 1024 + n] = acc[ms][ns][r] + bv_;
                }
            }
        }
    }
}

__global__ __launch_bounds__(256) void gemm_qkv(const u16* __restrict__ Xq, const u16* __restrict__ Xk,
                                                const u16* __restrict__ Xv,
                                                const u16* __restrict__ Wq, const u16* __restrict__ Wk,
                                                const u16* __restrict__ Wv,
                                                const float* __restrict__ bq, const float* __restrict__ bk,
                                                const float* __restrict__ bv,
                                                u16* __restrict__ Qh, u16* __restrict__ Kh,
                                                u16* __restrict__ VT) {
    int z = blockIdx.z;
    const u16* X = (z == 0) ? Xq : (z == 1) ? Xk : Xv;
    const u16* W = (z == 0) ? Wq : (z == 1) ? Wk : Wv;
    const float* bia = (z == 0) ? bq : (z == 1) ? bk : bv;
    if (z == 2)
        gemm_core<128, 1>(X, W, bia, (void*)VT, 1.0f, blockIdx.x, blockIdx.y);
    else if (z == 0)
        gemm_core<128, 0>(X, W, bia, (void*)Qh, 0.125f, blockIdx.x, blockIdx.y);
    else
        gemm_core<128, 0>(X, W, bia, (void*)Kh, 1.0f, blockIdx.x, blockIdx.y);
}

__global__ __launch_bounds__(256) void gemm_out(const u16* __restrict__ X, const u16* __restrict__ WT,
                                                const float* __restrict__ bias, float* __restrict__ outp) {
    gemm_core<64, 2>(X, WT, bias, outp, 1.0f, blockIdx.x, blockIdx.y);
}

// ---------------- fused attention: scores -> softmax -> attn write -> PV ----------------
// block: 16 q-rows of one (b,h); 4 waves, each covering 256 keys.
// 1D grid 4096, XCD-swizzled: bh % 8 == blockIdx.x % 8 so one bh's 64 q-blocks
// share an XCD (K/V strip fetched into that XCD's L2 once).
__global__ __launch_bounds__(256) void attn_fused(const u16* __restrict__ Qh, const u16* __restrict__ Kh,
                                                  const u16* __restrict__ VT,
                                                  float* __restrict__ attn_out, float* __restrict__ x_out) {
    __shared__ u16 P_lds[4][4096];      // [wave][16 rows x 256 keys], col XOR-swizzled
    __shared__ float red[4][16][64];    // PV cross-wave reduce
    __shared__ float redm[4][16];
    __shared__ float reds[4][16];
    int tid = threadIdx.x, l = tid & 63, w = tid >> 6;
    int lr = l & 15, lq = l >> 4;
    int wg = blockIdx.x;
    int xcd = wg & 7;
    int rest = wg >> 3;
    int q0 = (rest & 63) * 16;
    int bh = ((rest >> 6) << 3) | xcd;
    const u16* qp = Qh + (size_t)bh * 65536;
    const u16* kp = Kh + (size_t)bh * 65536;
    const u16* vp = VT + (size_t)bh * 65536;

    bf16x8 aq0 = *(const bf16x8*)(qp + (q0 + lr) * 64 + lq * 8);
    bf16x8 aq1 = *(const bf16x8*)(qp + (q0 + lr) * 64 + 32 + lq * 8);

    f32x4 sc[16];
#pragma unroll
    for (int n = 0; n < 16; n++) {
        int kb = w * 256 + n * 16;
        bf16x8 b0 = *(const bf16x8*)(kp + (size_t)(kb + lr) * 64 + lq * 8);
        bf16x8 b1 = *(const bf16x8*)(kp + (size_t)(kb + lr) * 64 + 32 + lq * 8);
        f32x4 a = {};
        a = __builtin_amdgcn_mfma_f32_16x16x32_bf16(aq0, b0, a, 0, 0, 0);
        a = __builtin_amdgcn_mfma_f32_16x16x32_bf16(aq1, b1, a, 0, 0, 0);
        sc[n] = a;
    }

    // row max: per-lane over 16 subtiles, then across 16 lanes, then across waves
#pragma unroll
    for (int r = 0; r < 4; r++) {
        float m = sc[0][r];
#pragma unroll
        for (int n = 1; n < 16; n++) m = fmaxf(m, sc[n][r]);
#pragma unroll
        for (int off = 1; off < 16; off <<= 1) m = fmaxf(m, __shfl_xor(m, off));
        if (lr == 0) redm[w][lq * 4 + r] = m;
    }
    __syncthreads();
    float inv[4];
#pragma unroll
    for (int r = 0; r < 4; r++) {
        int row = lq * 4 + r;
        float M = fmaxf(fmaxf(redm[0][row], redm[1][row]), fmaxf(redm[2][row], redm[3][row]));
        float s = 0.f;
#pragma unroll
        for (int n = 0; n < 16; n++) {
            float p = __expf(sc[n][r] - M);
            sc[n][r] = p;
            s += p;
        }
#pragma unroll
        for (int off = 1; off < 16; off <<= 1) s += __shfl_xor(s, off);
        if (lr == 0) reds[w][row] = s;
    }
    __syncthreads();
#pragma unroll
    for (int r = 0; r < 4; r++) {
        int row = lq * 4 + r;
        inv[r] = 1.0f / (reds[0][row] + reds[1][row] + reds[2][row] + reds[3][row]);
    }

    // write attn (f32, d_out) + stage P (bf16) into swizzled LDS for layout conversion
    size_t abase = (size_t)bh * 1048576 + (size_t)q0 * 1024 + w * 256;
#pragma unroll
    for (int n = 0; n < 16; n++) {
#pragma unroll
        for (int r = 0; r < 4; r++) {
            float p = sc[n][r] * inv[r];
            attn_out[abase + (size_t)(lq * 4 + r) * 1024 + n * 16 + lr] = p;
            int row = lq * 4 + r, col = n * 16 + lr;
            P_lds[w][row * 256 + (col ^ ((row & 3) << 4))] = f2bf(p);
        }
    }
    __syncthreads();

    // PV: P[16 x 256] @ V^T-slice -> [16 x 64] partial per wave
    f32x4 pv[4] = {};
#pragma unroll
    for (int kk = 0; kk < 8; kk++) {
        int col = kk * 32 + lq * 8;
        bf16x8 ap = *(const bf16x8*)(&P_lds[w][lr * 256 + (col ^ ((lr & 3) << 4))]);
#pragma unroll
        for (int ns = 0; ns < 4; ns++) {
            bf16x8 bv_ = *(const bf16x8*)(vp + (size_t)(ns * 16 + lr) * 1024 + w * 256 + kk * 32 + lq * 8);
            pv[ns] = __builtin_amdgcn_mfma_f32_16x16x32_bf16(ap, bv_, pv[ns], 0, 0, 0);
        }
    }
#pragma unroll
    for (int ns = 0; ns < 4; ns++)
#pragma unroll
        for (int r = 0; r < 4; r++)
            red[w][lq * 4 + r][ns * 16 + lr] = pv[ns][r];
    __syncthreads();

    int qq = tid >> 4, dk = (tid & 15) * 4;
    f32x4 acc = *(const f32x4*)&red[0][qq][dk];
#pragma unroll
    for (int w2 = 1; w2 < 4; w2++) acc += *(const f32x4*)&red[w2][qq][dk];
    int b = bh >> 4, h = bh & 15;
    *(f32x4*)(x_out + ((size_t)(b * 1024 + q0 + qq)) * 1024 + h * 64 + dk) = acc;
}

// ---------------- residual + LayerNorm -> bf16 ----------------
__global__ __launch_bounds__(256) void ln_kernel(const float* __restrict__ x, const float* __restrict__ resid,
                                                 const float* __restrict__ gamma, const float* __restrict__ beta,
                                                 u16* __restrict__ out) {
    int row = blockIdx.x, tid = threadIdx.x;
    int l = tid & 63, w = tid >> 6;
    size_t base = (size_t)row * 1024 + tid * 4;
    f32x4 v = *(const f32x4*)(x + base);
    f32x4 rz = *(const f32x4*)(resid + base);
    v += rz;
    float s = v[0] + v[1] + v[2] + v[3];
    float s2 = v[0] * v[0] + v[1] * v[1] + v[2] * v[2] + v[3] * v[3];
#pragma unroll
    for (int off = 1; off < 64; off <<= 1) {
        s += __shfl_xor(s, off);
        s2 += __shfl_xor(s2, off);
    }
    __shared__ float as_[4], as2_[4];
    if (l == 0) { as_[w] = s; as2_[w] = s2; }
    __syncthreads();
    s = as_[0] + as_[1] + as_[2] + as_[3];
    s2 = as2_[0] + as2_[1] + as2_[2] + as2_[3];
    float mean = s * (1.f / 1024.f);
    float var = s2 * (1.f / 1024.f) - mean * mean;
    float rs = rsqrtf(var + 1e-6f);
    f32x4 g = *(const f32x4*)(gamma + tid * 4);
    f32x4 bt = *(const f32x4*)(beta + tid * 4);
    us4 o;
    o.x = f2bf((v[0] - mean) * rs * g[0] + bt[0]);
    o.y = f2bf((v[1] - mean) * rs * g[1] + bt[1]);
    o.z = f2bf((v[2] - mean) * rs * g[2] + bt[2]);
    o.w = f2bf((v[3] - mean) * rs * g[3] + bt[3]);
    *(us4*)(out + base) = o;
}

extern "C" void kernel_launch(void* const* d_in, const int* in_sizes, int n_in,
                              void* d_out, int out_size, void* d_ws, size_t ws_size,
                              hipStream_t stream) {
    const float* query = (const float*)d_in[0];
    const float* key   = (const float*)d_in[1];
    const float* value = (const float*)d_in[2];
    const float* Wq    = (const float*)d_in[3];
    const float* bq    = (const float*)d_in[4];
    const float* Wk    = (const float*)d_in[5];
    const float* bk    = (const float*)d_in[6];
    const float* Wv    = (const float*)d_in[7];
    const float* bv    = (const float*)d_in[8];
    const float* Wo    = (const float*)d_in[9];
    const float* bo    = (const float*)d_in[10];
    const float* gamma = (const float*)d_in[11];
    const float* beta  = (const float*)d_in[12];

    char* ws = (char*)d_ws;
    u16* XQ  = (u16*)(ws + 0);          // 8 MiB  bf16 [4096][1024]
    u16* XK  = (u16*)(ws + 8388608);    // 8 MiB
    u16* XV  = (u16*)(ws + 16777216);   // 8 MiB
    u16* WQT = (u16*)(ws + 25165824);   // 2 MiB each
    u16* WKT = (u16*)(ws + 27262976);
    u16* WVT = (u16*)(ws + 29360128);
    u16* WOT = (u16*)(ws + 31457280);
    u16* Qh  = (u16*)(ws + 33554432);   // 8 MiB bf16 [B,H,S,DK] (pre-scaled by 1/8)
    u16* Kh  = (u16*)(ws + 41943040);   // 8 MiB bf16 [B,H,S,DK]
    u16* VT  = (u16*)(ws + 50331648);   // 8 MiB bf16 [B,H,DK,S]
    float* PV = (float*)(ws + 0);        // 16 MiB f32 [B,S,D] — overlaps XQ/XK (dead by then)
    u16* LN  = (u16*)(ws + 16777216);   // 8 MiB bf16 — overlaps XV (dead by then)

    float* outp = (float*)d_out;
    float* attn = outp + 4194304;

    cvt_x<<<dim3(4096, 3), 256, 0, stream>>>(query, key, value, XQ, XK, XV);
    cvt_w<<<dim3(16, 16, 4), 256, 0, stream>>>(Wq, Wk, Wv, Wo, WQT, WKT, WVT, WOT);
    gemm_qkv<<<dim3(32, 8, 3), 256, 0, stream>>>(XQ, XK, XV, WQT, WKT, WVT, bq, bk, bv, Qh, Kh, VT);
    attn_fused<<<dim3(4096), 256, 0, stream>>>(Qh, Kh, VT, attn, PV);
    ln_kernel<<<4096, 256, 0, stream>>>(PV, query, gamma, beta, LN);
    gemm_out<<<dim3(32, 16), 256, 0, stream>>>(LN, WOT, bo, outp);
}